// Round 5
// baseline (2121.723 us; speedup 1.0000x reference)
//
#include <hip/hip_runtime.h>
#include <hip/hip_bf16.h>

#define N_NODES 100000
#define N_EDGES 640000

typedef __bf16 bf16_t;
typedef __bf16 bf16x8 __attribute__((ext_vector_type(8)));
typedef float f32x4 __attribute__((ext_vector_type(4)));
typedef float f4 __attribute__((ext_vector_type(4)));
typedef unsigned int u32x4 __attribute__((ext_vector_type(4)));

// ---------------------------------------------------------------------------
// nodef f32 -> bf16 (25.6MB, cache-resident gather target)
// ---------------------------------------------------------------------------
__global__ __launch_bounds__(256)
void convert_nodef_kernel(const float* __restrict__ nodef,
                          unsigned short* __restrict__ nodef_bf) {
    int i = blockIdx.x * 256 + threadIdx.x;   // one float4 -> 4 bf16
    if (i < N_NODES * 32) {
        f4 v = *reinterpret_cast<const f4*>(nodef + (size_t)i * 4);
        union { bf16_t b[4]; unsigned long long ll; } pk;
        pk.b[0] = (bf16_t)v[0]; pk.b[1] = (bf16_t)v[1];
        pk.b[2] = (bf16_t)v[2]; pk.b[3] = (bf16_t)v[3];
        *reinterpret_cast<unsigned long long*>(nodef_bf + (size_t)i * 4) = pk.ll;
    }
}

// ---------------------------------------------------------------------------
// Prep: transpose + convert weights to bf16.
//   WtAB [256][384]: rows 0..127 = W_msg columns, rows 128..255 = W_rev columns
//   WtU  [128][128]: WtU[n][p] = W_upd[pi(p)][n], pi = msgs stored-column perm
// ---------------------------------------------------------------------------
__global__ void prep_weights_kernel(const float* __restrict__ Wmsg,
                                    const float* __restrict__ Wrev,
                                    const float* __restrict__ Wupd,
                                    bf16_t* __restrict__ WtAB,
                                    bf16_t* __restrict__ WtU) {
    int idx = blockIdx.x * 256 + threadIdx.x;
    if (idx < 256 * 384) {
        int n = idx / 384;
        int k = idx - n * 384;
        float v = (n < 128) ? Wmsg[k * 128 + n] : Wrev[k * 128 + (n - 128)];
        WtAB[idx] = (bf16_t)v;
    }
    if (idx < 128 * 128) {
        int n = idx >> 7;
        int p = idx & 127;
        int colp = 32 * (p >> 5) + ((p >> 1) & 15) + 16 * (p & 1);
        WtU[idx] = (bf16_t)Wupd[colp * 128 + n];
    }
}

// ---------------------------------------------------------------------------
// CSR build: hist -> hierarchical scan (coalesced) -> inverse permutation.
// ---------------------------------------------------------------------------
__global__ void hist_kernel(const int* __restrict__ to_idx, int* __restrict__ hist) {
    int e = blockIdx.x * 256 + threadIdx.x;
    if (e < N_EDGES) atomicAdd(&hist[to_idx[e]], 1);
}

#define SCAN_CH 1000  // N_NODES = 100 blocks x 1000

__global__ __launch_bounds__(1024)
void scan_reduce_kernel(const int* __restrict__ hist, int* __restrict__ bsum) {
    __shared__ int red[1024];
    int b = blockIdx.x, t = threadIdx.x;
    int v = (t < SCAN_CH) ? hist[b * SCAN_CH + t] : 0;
    red[t] = v;
    __syncthreads();
    for (int off = 512; off > 0; off >>= 1) {
        if (t < off) red[t] += red[t + off];
        __syncthreads();
    }
    if (t == 0) bsum[b] = red[0];
}

__global__ __launch_bounds__(128)
void scan_base_kernel(const int* __restrict__ bsum, int* __restrict__ bbase) {
    __shared__ int s[128];
    int t = threadIdx.x;
    int v = (t < 100) ? bsum[t] : 0;
    s[t] = v;
    __syncthreads();
    for (int off = 1; off < 128; off <<= 1) {
        int u = (t >= off) ? s[t - off] : 0;
        __syncthreads();
        s[t] += u;
        __syncthreads();
    }
    if (t < 100) bbase[t] = s[t] - v;  // exclusive base per block
}

__global__ __launch_bounds__(1024)
void scan_final_kernel(const int* __restrict__ hist,
                       const int* __restrict__ bbase,
                       int* __restrict__ cursor,
                       int* __restrict__ row_start) {
    __shared__ int s[1024];
    int b = blockIdx.x, t = threadIdx.x;
    int v = (t < SCAN_CH) ? hist[b * SCAN_CH + t] : 0;
    s[t] = v;
    __syncthreads();
    for (int off = 1; off < 1024; off <<= 1) {
        int u = (t >= off) ? s[t - off] : 0;
        __syncthreads();
        s[t] += u;
        __syncthreads();
    }
    int excl = bbase[b] + s[t] - v;
    if (t < SCAN_CH) {
        cursor[b * SCAN_CH + t] = excl;
        row_start[b * SCAN_CH + t] = excl;
    }
    if (b == 99 && t == SCAN_CH - 1) row_start[N_NODES] = excl + v;  // = N_EDGES
}

__global__ void inv_scatter_kernel(const int* __restrict__ to_idx,
                                   int* __restrict__ cursor,
                                   int* __restrict__ inv) {
    int e = blockIdx.x * 256 + threadIdx.x;
    if (e < N_EDGES) {
        int pos = atomicAdd(&cursor[to_idx[e]], 1);
        inv[e] = pos;
    }
}

// ---------------------------------------------------------------------------
// Phase A: per block of 64 edges, K split in two 192-col halves sharing one
// 24KB LDS tile (-> 6 blocks/CU for gather-latency hiding):
//   half0: [node_bf[from] | node_bf[to][0:64]]      -> LDS, MFMA ksteps 0..5
//   half1: [node_bf[to][64:128] | edgef (f32->bf16)] -> LDS, MFMA ksteps 6..11
//   relu(msg)+relu(rev), packed-bf16 store at dst-sorted position inv[e] (NT).
// Gathers are 256B bf16 rows from a 25.6MB cache-resident array; edgef loads
// and msgs stores are non-temporal to keep L3 for nodef_bf.
// ---------------------------------------------------------------------------
__global__ __launch_bounds__(256, 6)
void edge_msg_kernel(const unsigned short* __restrict__ nodef_bf,
                     const float* __restrict__ edgef,
                     const int* __restrict__ from_idx,
                     const int* __restrict__ to_idx,
                     const int* __restrict__ inv,
                     const bf16_t* __restrict__ WtAB,
                     const float* __restrict__ b_msg,
                     const float* __restrict__ b_rev,
                     unsigned int* __restrict__ msgs_u) {
    __shared__ char lds_raw[64 * 384];   // [64 rows][192 cols] bf16, XOR-swizzled
    __shared__ int s_from[64], s_dst[64], s_inv[64];

    const int tid = threadIdx.x;
    const int eb = blockIdx.x * 64;

    if (tid < 64) {
        s_from[tid] = from_idx[eb + tid];
        s_dst[tid]  = to_idx[eb + tid];
        s_inv[tid]  = inv[eb + tid];
    }

    const int wv = tid >> 6;
    const int lane = tid & 63;
    const int lhi = lane >> 4;   // 0..3
    const int llo = lane & 15;   // 0..15

    f32x4 acc[4][4];
#pragma unroll
    for (int m = 0; m < 4; ++m)
#pragma unroll
        for (int n = 0; n < 4; ++n)
            acc[m][n] = (f32x4){0.f, 0.f, 0.f, 0.f};

    // B pointers: n=0,1 -> msg cols wv*32+16n ; n=2,3 -> rev cols (+128)
    const bf16_t* bptr[4];
#pragma unroll
    for (int n = 0; n < 4; ++n) {
        int colb = (n < 2) ? (wv * 32 + 16 * n) : (128 + wv * 32 + 16 * (n - 2));
        bptr[n] = WtAB + (size_t)(colb + llo) * 384 + lhi * 8;
    }

    __syncthreads();

    // ---- half 0 stage: chunks 0..23 (16B each): q<16 from, else to[0:64]
#pragma unroll
    for (int j = 0; j < 6; ++j) {
        int linear = tid + 256 * j;
        int r = linear / 24;
        int q = linear - r * 24;
        const u32x4* src = (q < 16)
            ? reinterpret_cast<const u32x4*>(nodef_bf + (size_t)s_from[r] * 128) + q
            : reinterpret_cast<const u32x4*>(nodef_bf + (size_t)s_dst[r] * 128) + (q - 16);
        u32x4 v = *src;
        int byte = (r * 384 + q * 16) ^ ((r & 7) << 4);
        *reinterpret_cast<u32x4*>(lds_raw + byte) = v;
    }
    __syncthreads();

    // ---- MFMA half 0: global ksteps 0..5
#pragma unroll
    for (int k0 = 0; k0 < 6; ++k0) {
        bf16x8 a[4], b[4];
#pragma unroll
        for (int m = 0; m < 4; ++m) {
            int ra = 16 * m + llo;
            int byte = (ra * 384 + k0 * 64 + lhi * 16) ^ ((ra & 7) << 4);
            a[m] = *reinterpret_cast<const bf16x8*>(lds_raw + byte);
        }
#pragma unroll
        for (int n = 0; n < 4; ++n)
            b[n] = *reinterpret_cast<const bf16x8*>(bptr[n] + k0 * 32);
#pragma unroll
        for (int m = 0; m < 4; ++m)
#pragma unroll
            for (int n = 0; n < 4; ++n)
                acc[m][n] = __builtin_amdgcn_mfma_f32_16x16x32_bf16(a[m], b[n], acc[m][n], 0, 0, 0);
    }
    __syncthreads();

    // ---- half 1 stage: chunks 24..47: qq<8 -> to[64:128], else edgef f32->bf16
#pragma unroll
    for (int j = 0; j < 6; ++j) {
        int linear = tid + 256 * j;
        int r = linear / 24;
        int qq = linear - r * 24;
        u32x4 w;
        if (qq < 8) {
            w = *(reinterpret_cast<const u32x4*>(nodef_bf + (size_t)s_dst[r] * 128) + 8 + qq);
        } else {
            int c = qq - 8;   // 0..15 -> source floats 8c..8c+7
            const f4* ep = reinterpret_cast<const f4*>(edgef + (size_t)(eb + r) * 128 + c * 8);
            f4 v0 = __builtin_nontemporal_load(ep);
            f4 v1 = __builtin_nontemporal_load(ep + 1);
            union { bf16_t b[8]; u32x4 u; } pk;
            pk.b[0] = (bf16_t)v0[0]; pk.b[1] = (bf16_t)v0[1];
            pk.b[2] = (bf16_t)v0[2]; pk.b[3] = (bf16_t)v0[3];
            pk.b[4] = (bf16_t)v1[0]; pk.b[5] = (bf16_t)v1[1];
            pk.b[6] = (bf16_t)v1[2]; pk.b[7] = (bf16_t)v1[3];
            w = pk.u;
        }
        int byte = (r * 384 + qq * 16) ^ ((r & 7) << 4);
        *reinterpret_cast<u32x4*>(lds_raw + byte) = w;
    }
    __syncthreads();

    // ---- MFMA half 1: global ksteps 6..11
#pragma unroll
    for (int k0 = 0; k0 < 6; ++k0) {
        bf16x8 a[4], b[4];
#pragma unroll
        for (int m = 0; m < 4; ++m) {
            int ra = 16 * m + llo;
            int byte = (ra * 384 + k0 * 64 + lhi * 16) ^ ((ra & 7) << 4);
            a[m] = *reinterpret_cast<const bf16x8*>(lds_raw + byte);
        }
#pragma unroll
        for (int n = 0; n < 4; ++n)
            b[n] = *reinterpret_cast<const bf16x8*>(bptr[n] + (6 + k0) * 32);
#pragma unroll
        for (int m = 0; m < 4; ++m)
#pragma unroll
            for (int n = 0; n < 4; ++n)
                acc[m][n] = __builtin_amdgcn_mfma_f32_16x16x32_bf16(a[m], b[n], acc[m][n], 0, 0, 0);
    }

    // ---- epilogue: relu-sum both nets, pack bf16 pair, NT store at inv row ----
    const int c0 = wv * 32 + llo;
    const float bm0 = b_msg[c0], br0 = b_rev[c0];
    const float bm1 = b_msg[c0 + 16], br1 = b_rev[c0 + 16];
#pragma unroll
    for (int m = 0; m < 4; ++m) {
        int rbase = 16 * m + lhi * 4;
#pragma unroll
        for (int r = 0; r < 4; ++r) {
            float v0 = fmaxf(acc[m][0][r] + bm0, 0.f) + fmaxf(acc[m][2][r] + br0, 0.f);
            float v1 = fmaxf(acc[m][1][r] + bm1, 0.f) + fmaxf(acc[m][3][r] + br1, 0.f);
            union { bf16_t b[2]; unsigned int u; } pk;
            pk.b[0] = (bf16_t)v0;
            pk.b[1] = (bf16_t)v1;
            __builtin_nontemporal_store(
                pk.u, &msgs_u[(size_t)s_inv[rbase + r] * 64 + wv * 16 + llo]);
        }
    }
}

// ---------------------------------------------------------------------------
// Phase B: per block of 64 nodes:
//   f32 register segsum of each node's CONTIGUOUS msgs range (CSR, NT loads),
//   -> bf16 LDS tile [64][128] (swizzled, stored-column order),
//   MFMA with pi-baked WtU, residual + relu, store out.
// ---------------------------------------------------------------------------
__global__ __launch_bounds__(256, 4)
void node_upd_kernel(const unsigned int* __restrict__ msgs_u,
                     const int* __restrict__ row_start,
                     const float* __restrict__ nodef,
                     const bf16_t* __restrict__ WtU,
                     const float* __restrict__ b_upd,
                     float* __restrict__ out) {
    __shared__ char lds_raw[64 * 256];  // [64][128] bf16, swizzled
    __shared__ int s_rs[65];

    const int tid = threadIdx.x;
    const int nb = blockIdx.x * 64;

    if (tid < 65) {
        int nid = nb + tid;
        s_rs[tid] = (nid <= N_NODES) ? row_start[nid] : N_EDGES;
    }
    __syncthreads();

    {
        const int r = tid >> 2;      // node row 0..63
        const int q = tid & 3;       // 32-column chunk
        float s[32];
#pragma unroll
        for (int i = 0; i < 32; ++i) s[i] = 0.f;
        const int rs = s_rs[r], re = s_rs[r + 1];
        for (int e = rs; e < re; ++e) {
            const u32x4* p = reinterpret_cast<const u32x4*>(msgs_u + (size_t)e * 64 + q * 16);
#pragma unroll
            for (int i = 0; i < 4; ++i) {
                u32x4 w = __builtin_nontemporal_load(p + i);
                s[8*i+0] += __uint_as_float(w[0] << 16);
                s[8*i+1] += __uint_as_float(w[0] & 0xffff0000u);
                s[8*i+2] += __uint_as_float(w[1] << 16);
                s[8*i+3] += __uint_as_float(w[1] & 0xffff0000u);
                s[8*i+4] += __uint_as_float(w[2] << 16);
                s[8*i+5] += __uint_as_float(w[2] & 0xffff0000u);
                s[8*i+6] += __uint_as_float(w[3] << 16);
                s[8*i+7] += __uint_as_float(w[3] & 0xffff0000u);
            }
        }
        // bf16-pack into LDS (swizzled), stored-column order
#pragma unroll
        for (int i = 0; i < 4; ++i) {
            union { bf16_t b[8]; u32x4 u; } pk;
#pragma unroll
            for (int w = 0; w < 8; ++w) pk.b[w] = (bf16_t)s[8*i + w];
            int byte = (r * 256 + q * 64 + i * 16) ^ ((r & 7) << 4);
            *reinterpret_cast<u32x4*>(lds_raw + byte) = pk.u;
        }
    }
    __syncthreads();

    const int wv = tid >> 6;
    const int lane = tid & 63;
    const int lhi = lane >> 4;
    const int llo = lane & 15;

    f32x4 acc[4][2];
#pragma unroll
    for (int m = 0; m < 4; ++m)
#pragma unroll
        for (int n = 0; n < 2; ++n)
            acc[m][n] = (f32x4){0.f, 0.f, 0.f, 0.f};

#pragma unroll
    for (int k0 = 0; k0 < 4; ++k0) {
        bf16x8 a[4], b[2];
#pragma unroll
        for (int m = 0; m < 4; ++m) {
            int ra = 16 * m + llo;
            int byte = (ra * 256 + (k0 * 32 + lhi * 8) * 2) ^ ((ra & 7) << 4);
            a[m] = *reinterpret_cast<const bf16x8*>(lds_raw + byte);
        }
#pragma unroll
        for (int n = 0; n < 2; ++n) {
            int col = wv * 32 + 16 * n + llo;
            b[n] = *reinterpret_cast<const bf16x8*>(WtU + (size_t)col * 128 + k0 * 32 + lhi * 8);
        }
#pragma unroll
        for (int m = 0; m < 4; ++m)
#pragma unroll
            for (int n = 0; n < 2; ++n)
                acc[m][n] = __builtin_amdgcn_mfma_f32_16x16x32_bf16(a[m], b[n], acc[m][n], 0, 0, 0);
    }

#pragma unroll
    for (int m = 0; m < 4; ++m) {
        int rbase = 16 * m + lhi * 4;
#pragma unroll
        for (int r = 0; r < 4; ++r) {
            int i = nb + rbase + r;
            if (i < N_NODES) {
#pragma unroll
                for (int n = 0; n < 2; ++n) {
                    int c = wv * 32 + 16 * n + llo;
                    out[(size_t)i * 128 + c] =
                        nodef[(size_t)i * 128 + c]
                        + fmaxf(acc[m][n][r] + b_upd[c], 0.f);
                }
            }
        }
    }
}

// ---------------------------------------------------------------------------
extern "C" void kernel_launch(void* const* d_in, const int* in_sizes, int n_in,
                              void* d_out, int out_size, void* d_ws, size_t ws_size,
                              hipStream_t stream) {
    const float* nodef    = (const float*)d_in[0];
    const float* edgef    = (const float*)d_in[1];
    const int*   from_idx = (const int*)d_in[2];
    const int*   to_idx   = (const int*)d_in[3];
    const float* Wmsg     = (const float*)d_in[4];
    const float* bmsg     = (const float*)d_in[5];
    const float* Wrev     = (const float*)d_in[6];
    const float* brev     = (const float*)d_in[7];
    const float* Wupd     = (const float*)d_in[8];
    const float* bupd     = (const float*)d_in[9];
    float* out = (float*)d_out;

    char* ws = (char*)d_ws;
    unsigned int*   msgs_u   = (unsigned int*)ws;              // 163,840,000 B
    bf16_t*         WtAB     = (bf16_t*)(ws + 163840000);      // 196,608 B
    bf16_t*         WtU      = (bf16_t*)(ws + 164036608);      // 32,768 B
    unsigned short* nodef_bf = (unsigned short*)(ws + 164069376); // 25,600,000 B
    int*            hist     = (int*)(ws + 189669376);         // 400,000 B
    int*            cursor   = (int*)(ws + 190069376);         // 400,000 B
    int*            rowstart = (int*)(ws + 190469376);         // 400,016 B
    int*            inv      = (int*)(ws + 190869392);         // 2,560,000 B
    int*            bsum     = (int*)(ws + 193429392);         // 400 B
    int*            bbase    = (int*)(ws + 193429792);         // 400 B
                                                               // total ~193.4 MB

    hipMemsetAsync(hist, 0, (size_t)N_NODES * sizeof(int), stream);

    convert_nodef_kernel<<<12500, 256, 0, stream>>>(nodef, nodef_bf);
    prep_weights_kernel<<<384, 256, 0, stream>>>(Wmsg, Wrev, Wupd, WtAB, WtU);
    hist_kernel<<<(N_EDGES + 255) / 256, 256, 0, stream>>>(to_idx, hist);
    scan_reduce_kernel<<<100, 1024, 0, stream>>>(hist, bsum);
    scan_base_kernel<<<1, 128, 0, stream>>>(bsum, bbase);
    scan_final_kernel<<<100, 1024, 0, stream>>>(hist, bbase, cursor, rowstart);
    inv_scatter_kernel<<<(N_EDGES + 255) / 256, 256, 0, stream>>>(to_idx, cursor, inv);
    edge_msg_kernel<<<N_EDGES / 64, 256, 0, stream>>>(
        nodef_bf, edgef, from_idx, to_idx, inv, WtAB, bmsg, brev, msgs_u);
    node_upd_kernel<<<(N_NODES + 63) / 64, 256, 0, stream>>>(
        msgs_u, rowstart, nodef, WtU, bupd, out);
}

// Round 6
// 2120.820 us; speedup vs baseline: 1.0004x; 1.0004x over previous
//
#include <hip/hip_runtime.h>
#include <hip/hip_bf16.h>

#define N_NODES 100000
#define N_EDGES 640000

typedef __bf16 bf16_t;
typedef __bf16 bf16x8 __attribute__((ext_vector_type(8)));
typedef float f32x4 __attribute__((ext_vector_type(4)));
typedef float f4 __attribute__((ext_vector_type(4)));
typedef unsigned int u32x4 __attribute__((ext_vector_type(4)));

// ---------------------------------------------------------------------------
// nodef f32 -> bf16 (25.6MB, cache-resident gather target)
// ---------------------------------------------------------------------------
__global__ __launch_bounds__(256)
void convert_nodef_kernel(const float* __restrict__ nodef,
                          unsigned short* __restrict__ nodef_bf) {
    int i = blockIdx.x * 256 + threadIdx.x;   // one float4 -> 4 bf16
    if (i < N_NODES * 32) {
        f4 v = *reinterpret_cast<const f4*>(nodef + (size_t)i * 4);
        union { bf16_t b[4]; unsigned long long ll; } pk;
        pk.b[0] = (bf16_t)v[0]; pk.b[1] = (bf16_t)v[1];
        pk.b[2] = (bf16_t)v[2]; pk.b[3] = (bf16_t)v[3];
        *reinterpret_cast<unsigned long long*>(nodef_bf + (size_t)i * 4) = pk.ll;
    }
}

// ---------------------------------------------------------------------------
// Prep: transpose + convert weights to bf16.
//   WtAB [256][384]: rows 0..127 = W_msg columns, rows 128..255 = W_rev columns
//   WtU  [128][128]: WtU[n][p] = W_upd[pi(p)][n], pi = msgs stored-column perm
// ---------------------------------------------------------------------------
__global__ void prep_weights_kernel(const float* __restrict__ Wmsg,
                                    const float* __restrict__ Wrev,
                                    const float* __restrict__ Wupd,
                                    bf16_t* __restrict__ WtAB,
                                    bf16_t* __restrict__ WtU) {
    int idx = blockIdx.x * 256 + threadIdx.x;
    if (idx < 256 * 384) {
        int n = idx / 384;
        int k = idx - n * 384;
        float v = (n < 128) ? Wmsg[k * 128 + n] : Wrev[k * 128 + (n - 128)];
        WtAB[idx] = (bf16_t)v;
    }
    if (idx < 128 * 128) {
        int n = idx >> 7;
        int p = idx & 127;
        int colp = 32 * (p >> 5) + ((p >> 1) & 15) + 16 * (p & 1);
        WtU[idx] = (bf16_t)Wupd[colp * 128 + n];
    }
}

// ---------------------------------------------------------------------------
// CSR build: hist -> hierarchical scan (coalesced) -> inverse permutation.
// ---------------------------------------------------------------------------
__global__ void hist_kernel(const int* __restrict__ to_idx, int* __restrict__ hist) {
    int e = blockIdx.x * 256 + threadIdx.x;
    if (e < N_EDGES) atomicAdd(&hist[to_idx[e]], 1);
}

#define SCAN_CH 1000  // N_NODES = 100 blocks x 1000

__global__ __launch_bounds__(1024)
void scan_reduce_kernel(const int* __restrict__ hist, int* __restrict__ bsum) {
    __shared__ int red[1024];
    int b = blockIdx.x, t = threadIdx.x;
    int v = (t < SCAN_CH) ? hist[b * SCAN_CH + t] : 0;
    red[t] = v;
    __syncthreads();
    for (int off = 512; off > 0; off >>= 1) {
        if (t < off) red[t] += red[t + off];
        __syncthreads();
    }
    if (t == 0) bsum[b] = red[0];
}

__global__ __launch_bounds__(128)
void scan_base_kernel(const int* __restrict__ bsum, int* __restrict__ bbase) {
    __shared__ int s[128];
    int t = threadIdx.x;
    int v = (t < 100) ? bsum[t] : 0;
    s[t] = v;
    __syncthreads();
    for (int off = 1; off < 128; off <<= 1) {
        int u = (t >= off) ? s[t - off] : 0;
        __syncthreads();
        s[t] += u;
        __syncthreads();
    }
    if (t < 100) bbase[t] = s[t] - v;  // exclusive base per block
}

__global__ __launch_bounds__(1024)
void scan_final_kernel(const int* __restrict__ hist,
                       const int* __restrict__ bbase,
                       int* __restrict__ cursor,
                       int* __restrict__ row_start) {
    __shared__ int s[1024];
    int b = blockIdx.x, t = threadIdx.x;
    int v = (t < SCAN_CH) ? hist[b * SCAN_CH + t] : 0;
    s[t] = v;
    __syncthreads();
    for (int off = 1; off < 1024; off <<= 1) {
        int u = (t >= off) ? s[t - off] : 0;
        __syncthreads();
        s[t] += u;
        __syncthreads();
    }
    int excl = bbase[b] + s[t] - v;
    if (t < SCAN_CH) {
        cursor[b * SCAN_CH + t] = excl;
        row_start[b * SCAN_CH + t] = excl;
    }
    if (b == 99 && t == SCAN_CH - 1) row_start[N_NODES] = excl + v;  // = N_EDGES
}

__global__ void inv_scatter_kernel(const int* __restrict__ to_idx,
                                   int* __restrict__ cursor,
                                   int* __restrict__ inv) {
    int e = blockIdx.x * 256 + threadIdx.x;
    if (e < N_EDGES) {
        int pos = atomicAdd(&cursor[to_idx[e]], 1);
        inv[e] = pos;
    }
}

// ---------------------------------------------------------------------------
// Phase A: per block of 64 edges, K split in two 192-col halves sharing one
// 24KB LDS tile (-> 6 blocks/CU for gather-latency hiding):
//   half0: [node_bf[from] | node_bf[to][0:64]]       -> LDS, MFMA ksteps 0..5
//   half1: [node_bf[to][64:128] | edgef (f32->bf16)] -> LDS, MFMA ksteps 6..11
//   relu(msg)+relu(rev), packed-bf16 store at dst-sorted position inv[e].
// NO non-temporal hints anywhere (r5 lesson: NT stores on partial lines
// caused 27x HBM write amplification on gfx950).
// ---------------------------------------------------------------------------
__global__ __launch_bounds__(256, 6)
void edge_msg_kernel(const unsigned short* __restrict__ nodef_bf,
                     const float* __restrict__ edgef,
                     const int* __restrict__ from_idx,
                     const int* __restrict__ to_idx,
                     const int* __restrict__ inv,
                     const bf16_t* __restrict__ WtAB,
                     const float* __restrict__ b_msg,
                     const float* __restrict__ b_rev,
                     unsigned int* __restrict__ msgs_u) {
    __shared__ char lds_raw[64 * 384];   // [64 rows][192 cols] bf16, XOR-swizzled
    __shared__ int s_from[64], s_dst[64], s_inv[64];

    const int tid = threadIdx.x;
    const int eb = blockIdx.x * 64;

    if (tid < 64) {
        s_from[tid] = from_idx[eb + tid];
        s_dst[tid]  = to_idx[eb + tid];
        s_inv[tid]  = inv[eb + tid];
    }

    const int wv = tid >> 6;
    const int lane = tid & 63;
    const int lhi = lane >> 4;   // 0..3
    const int llo = lane & 15;   // 0..15

    f32x4 acc[4][4];
#pragma unroll
    for (int m = 0; m < 4; ++m)
#pragma unroll
        for (int n = 0; n < 4; ++n)
            acc[m][n] = (f32x4){0.f, 0.f, 0.f, 0.f};

    // B pointers: n=0,1 -> msg cols wv*32+16n ; n=2,3 -> rev cols (+128)
    const bf16_t* bptr[4];
#pragma unroll
    for (int n = 0; n < 4; ++n) {
        int colb = (n < 2) ? (wv * 32 + 16 * n) : (128 + wv * 32 + 16 * (n - 2));
        bptr[n] = WtAB + (size_t)(colb + llo) * 384 + lhi * 8;
    }

    __syncthreads();

    // ---- half 0 stage: chunks 0..23 (16B each): q<16 from, else to[0:64]
#pragma unroll
    for (int j = 0; j < 6; ++j) {
        int linear = tid + 256 * j;
        int r = linear / 24;
        int q = linear - r * 24;
        const u32x4* src = (q < 16)
            ? reinterpret_cast<const u32x4*>(nodef_bf + (size_t)s_from[r] * 128) + q
            : reinterpret_cast<const u32x4*>(nodef_bf + (size_t)s_dst[r] * 128) + (q - 16);
        u32x4 v = *src;
        int byte = (r * 384 + q * 16) ^ ((r & 7) << 4);
        *reinterpret_cast<u32x4*>(lds_raw + byte) = v;
    }
    __syncthreads();

    // ---- MFMA half 0: global ksteps 0..5
#pragma unroll
    for (int k0 = 0; k0 < 6; ++k0) {
        bf16x8 a[4], b[4];
#pragma unroll
        for (int m = 0; m < 4; ++m) {
            int ra = 16 * m + llo;
            int byte = (ra * 384 + k0 * 64 + lhi * 16) ^ ((ra & 7) << 4);
            a[m] = *reinterpret_cast<const bf16x8*>(lds_raw + byte);
        }
#pragma unroll
        for (int n = 0; n < 4; ++n)
            b[n] = *reinterpret_cast<const bf16x8*>(bptr[n] + k0 * 32);
#pragma unroll
        for (int m = 0; m < 4; ++m)
#pragma unroll
            for (int n = 0; n < 4; ++n)
                acc[m][n] = __builtin_amdgcn_mfma_f32_16x16x32_bf16(a[m], b[n], acc[m][n], 0, 0, 0);
    }
    __syncthreads();

    // ---- half 1 stage: chunks 24..47: qq<8 -> to[64:128], else edgef f32->bf16
#pragma unroll
    for (int j = 0; j < 6; ++j) {
        int linear = tid + 256 * j;
        int r = linear / 24;
        int qq = linear - r * 24;
        u32x4 w;
        if (qq < 8) {
            w = *(reinterpret_cast<const u32x4*>(nodef_bf + (size_t)s_dst[r] * 128) + 8 + qq);
        } else {
            int c = qq - 8;   // 0..15 -> source floats 8c..8c+7
            const f4* ep = reinterpret_cast<const f4*>(edgef + (size_t)(eb + r) * 128 + c * 8);
            f4 v0 = ep[0];
            f4 v1 = ep[1];
            union { bf16_t b[8]; u32x4 u; } pk;
            pk.b[0] = (bf16_t)v0[0]; pk.b[1] = (bf16_t)v0[1];
            pk.b[2] = (bf16_t)v0[2]; pk.b[3] = (bf16_t)v0[3];
            pk.b[4] = (bf16_t)v1[0]; pk.b[5] = (bf16_t)v1[1];
            pk.b[6] = (bf16_t)v1[2]; pk.b[7] = (bf16_t)v1[3];
            w = pk.u;
        }
        int byte = (r * 384 + qq * 16) ^ ((r & 7) << 4);
        *reinterpret_cast<u32x4*>(lds_raw + byte) = w;
    }
    __syncthreads();

    // ---- MFMA half 1: global ksteps 6..11
#pragma unroll
    for (int k0 = 0; k0 < 6; ++k0) {
        bf16x8 a[4], b[4];
#pragma unroll
        for (int m = 0; m < 4; ++m) {
            int ra = 16 * m + llo;
            int byte = (ra * 384 + k0 * 64 + lhi * 16) ^ ((ra & 7) << 4);
            a[m] = *reinterpret_cast<const bf16x8*>(lds_raw + byte);
        }
#pragma unroll
        for (int n = 0; n < 4; ++n)
            b[n] = *reinterpret_cast<const bf16x8*>(bptr[n] + (6 + k0) * 32);
#pragma unroll
        for (int m = 0; m < 4; ++m)
#pragma unroll
            for (int n = 0; n < 4; ++n)
                acc[m][n] = __builtin_amdgcn_mfma_f32_16x16x32_bf16(a[m], b[n], acc[m][n], 0, 0, 0);
    }

    // ---- epilogue: relu-sum both nets, pack bf16 pair, store at inv row ----
    const int c0 = wv * 32 + llo;
    const float bm0 = b_msg[c0], br0 = b_rev[c0];
    const float bm1 = b_msg[c0 + 16], br1 = b_rev[c0 + 16];
#pragma unroll
    for (int m = 0; m < 4; ++m) {
        int rbase = 16 * m + lhi * 4;
#pragma unroll
        for (int r = 0; r < 4; ++r) {
            float v0 = fmaxf(acc[m][0][r] + bm0, 0.f) + fmaxf(acc[m][2][r] + br0, 0.f);
            float v1 = fmaxf(acc[m][1][r] + bm1, 0.f) + fmaxf(acc[m][3][r] + br1, 0.f);
            union { bf16_t b[2]; unsigned int u; } pk;
            pk.b[0] = (bf16_t)v0;
            pk.b[1] = (bf16_t)v1;
            msgs_u[(size_t)s_inv[rbase + r] * 64 + wv * 16 + llo] = pk.u;
        }
    }
}

// ---------------------------------------------------------------------------
// Phase B: per block of 64 nodes:
//   f32 register segsum of each node's CONTIGUOUS msgs range (CSR),
//   -> bf16 LDS tile [64][128] (swizzled, stored-column order),
//   MFMA with pi-baked WtU, residual + relu, store out.
// ---------------------------------------------------------------------------
__global__ __launch_bounds__(256, 4)
void node_upd_kernel(const unsigned int* __restrict__ msgs_u,
                     const int* __restrict__ row_start,
                     const float* __restrict__ nodef,
                     const bf16_t* __restrict__ WtU,
                     const float* __restrict__ b_upd,
                     float* __restrict__ out) {
    __shared__ char lds_raw[64 * 256];  // [64][128] bf16, swizzled
    __shared__ int s_rs[65];

    const int tid = threadIdx.x;
    const int nb = blockIdx.x * 64;

    if (tid < 65) {
        int nid = nb + tid;
        s_rs[tid] = (nid <= N_NODES) ? row_start[nid] : N_EDGES;
    }
    __syncthreads();

    {
        const int r = tid >> 2;      // node row 0..63
        const int q = tid & 3;       // 32-column chunk
        float s[32];
#pragma unroll
        for (int i = 0; i < 32; ++i) s[i] = 0.f;
        const int rs = s_rs[r], re = s_rs[r + 1];
        for (int e = rs; e < re; ++e) {
            const u32x4* p = reinterpret_cast<const u32x4*>(msgs_u + (size_t)e * 64 + q * 16);
#pragma unroll
            for (int i = 0; i < 4; ++i) {
                u32x4 w = p[i];
                s[8*i+0] += __uint_as_float(w[0] << 16);
                s[8*i+1] += __uint_as_float(w[0] & 0xffff0000u);
                s[8*i+2] += __uint_as_float(w[1] << 16);
                s[8*i+3] += __uint_as_float(w[1] & 0xffff0000u);
                s[8*i+4] += __uint_as_float(w[2] << 16);
                s[8*i+5] += __uint_as_float(w[2] & 0xffff0000u);
                s[8*i+6] += __uint_as_float(w[3] << 16);
                s[8*i+7] += __uint_as_float(w[3] & 0xffff0000u);
            }
        }
        // bf16-pack into LDS (swizzled), stored-column order
#pragma unroll
        for (int i = 0; i < 4; ++i) {
            union { bf16_t b[8]; u32x4 u; } pk;
#pragma unroll
            for (int w = 0; w < 8; ++w) pk.b[w] = (bf16_t)s[8*i + w];
            int byte = (r * 256 + q * 64 + i * 16) ^ ((r & 7) << 4);
            *reinterpret_cast<u32x4*>(lds_raw + byte) = pk.u;
        }
    }
    __syncthreads();

    const int wv = tid >> 6;
    const int lane = tid & 63;
    const int lhi = lane >> 4;
    const int llo = lane & 15;

    f32x4 acc[4][2];
#pragma unroll
    for (int m = 0; m < 4; ++m)
#pragma unroll
        for (int n = 0; n < 2; ++n)
            acc[m][n] = (f32x4){0.f, 0.f, 0.f, 0.f};

#pragma unroll
    for (int k0 = 0; k0 < 4; ++k0) {
        bf16x8 a[4], b[2];
#pragma unroll
        for (int m = 0; m < 4; ++m) {
            int ra = 16 * m + llo;
            int byte = (ra * 256 + (k0 * 32 + lhi * 8) * 2) ^ ((ra & 7) << 4);
            a[m] = *reinterpret_cast<const bf16x8*>(lds_raw + byte);
        }
#pragma unroll
        for (int n = 0; n < 2; ++n) {
            int col = wv * 32 + 16 * n + llo;
            b[n] = *reinterpret_cast<const bf16x8*>(WtU + (size_t)col * 128 + k0 * 32 + lhi * 8);
        }
#pragma unroll
        for (int m = 0; m < 4; ++m)
#pragma unroll
            for (int n = 0; n < 2; ++n)
                acc[m][n] = __builtin_amdgcn_mfma_f32_16x16x32_bf16(a[m], b[n], acc[m][n], 0, 0, 0);
    }

#pragma unroll
    for (int m = 0; m < 4; ++m) {
        int rbase = 16 * m + lhi * 4;
#pragma unroll
        for (int r = 0; r < 4; ++r) {
            int i = nb + rbase + r;
            if (i < N_NODES) {
#pragma unroll
                for (int n = 0; n < 2; ++n) {
                    int c = wv * 32 + 16 * n + llo;
                    out[(size_t)i * 128 + c] =
                        nodef[(size_t)i * 128 + c]
                        + fmaxf(acc[m][n][r] + b_upd[c], 0.f);
                }
            }
        }
    }
}

// ---------------------------------------------------------------------------
extern "C" void kernel_launch(void* const* d_in, const int* in_sizes, int n_in,
                              void* d_out, int out_size, void* d_ws, size_t ws_size,
                              hipStream_t stream) {
    const float* nodef    = (const float*)d_in[0];
    const float* edgef    = (const float*)d_in[1];
    const int*   from_idx = (const int*)d_in[2];
    const int*   to_idx   = (const int*)d_in[3];
    const float* Wmsg     = (const float*)d_in[4];
    const float* bmsg     = (const float*)d_in[5];
    const float* Wrev     = (const float*)d_in[6];
    const float* brev     = (const float*)d_in[7];
    const float* Wupd     = (const float*)d_in[8];
    const float* bupd     = (const float*)d_in[9];
    float* out = (float*)d_out;

    char* ws = (char*)d_ws;
    unsigned int*   msgs_u   = (unsigned int*)ws;              // 163,840,000 B
    bf16_t*         WtAB     = (bf16_t*)(ws + 163840000);      // 196,608 B
    bf16_t*         WtU      = (bf16_t*)(ws + 164036608);      // 32,768 B
    unsigned short* nodef_bf = (unsigned short*)(ws + 164069376); // 25,600,000 B
    int*            hist     = (int*)(ws + 189669376);         // 400,000 B
    int*            cursor   = (int*)(ws + 190069376);         // 400,000 B
    int*            rowstart = (int*)(ws + 190469376);         // 400,016 B
    int*            inv      = (int*)(ws + 190869392);         // 2,560,000 B
    int*            bsum     = (int*)(ws + 193429392);         // 400 B
    int*            bbase    = (int*)(ws + 193429792);         // 400 B
                                                               // total ~193.4 MB

    hipMemsetAsync(hist, 0, (size_t)N_NODES * sizeof(int), stream);

    convert_nodef_kernel<<<12500, 256, 0, stream>>>(nodef, nodef_bf);
    prep_weights_kernel<<<384, 256, 0, stream>>>(Wmsg, Wrev, Wupd, WtAB, WtU);
    hist_kernel<<<(N_EDGES + 255) / 256, 256, 0, stream>>>(to_idx, hist);
    scan_reduce_kernel<<<100, 1024, 0, stream>>>(hist, bsum);
    scan_base_kernel<<<1, 128, 0, stream>>>(bsum, bbase);
    scan_final_kernel<<<100, 1024, 0, stream>>>(hist, bbase, cursor, rowstart);
    inv_scatter_kernel<<<(N_EDGES + 255) / 256, 256, 0, stream>>>(to_idx, cursor, inv);
    edge_msg_kernel<<<N_EDGES / 64, 256, 0, stream>>>(
        nodef_bf, edgef, from_idx, to_idx, inv, WtAB, bmsg, brev, msgs_u);
    node_upd_kernel<<<(N_NODES + 63) / 64, 256, 0, stream>>>(
        msgs_u, rowstart, nodef, WtU, bupd, out);
}

// Round 7
// 639.603 us; speedup vs baseline: 3.3172x; 3.3158x over previous
//
#include <hip/hip_runtime.h>
#include <hip/hip_bf16.h>

#define N_NODES 100000
#define N_EDGES 640000

typedef __bf16 bf16_t;
typedef __bf16 bf16x8 __attribute__((ext_vector_type(8)));
typedef float f32x4 __attribute__((ext_vector_type(4)));
typedef float f4 __attribute__((ext_vector_type(4)));
typedef unsigned int u32x4 __attribute__((ext_vector_type(4)));

// ---------------------------------------------------------------------------
// nodef f32 -> bf16 (25.6MB, cache-resident gather target)
// ---------------------------------------------------------------------------
__global__ __launch_bounds__(256)
void convert_nodef_kernel(const float* __restrict__ nodef,
                          unsigned short* __restrict__ nodef_bf) {
    int i = blockIdx.x * 256 + threadIdx.x;   // one float4 -> 4 bf16
    if (i < N_NODES * 32) {
        f4 v = *reinterpret_cast<const f4*>(nodef + (size_t)i * 4);
        union { bf16_t b[4]; unsigned long long ll; } pk;
        pk.b[0] = (bf16_t)v[0]; pk.b[1] = (bf16_t)v[1];
        pk.b[2] = (bf16_t)v[2]; pk.b[3] = (bf16_t)v[3];
        *reinterpret_cast<unsigned long long*>(nodef_bf + (size_t)i * 4) = pk.ll;
    }
}

// ---------------------------------------------------------------------------
// Prep: transpose + convert weights to bf16.
//   WtAB [256][384]: rows 0..127 = W_msg columns, rows 128..255 = W_rev columns
//   WtU  [128][128]: WtU[n][p] = W_upd[pi(p)][n], pi = msgs stored-column perm
// ---------------------------------------------------------------------------
__global__ void prep_weights_kernel(const float* __restrict__ Wmsg,
                                    const float* __restrict__ Wrev,
                                    const float* __restrict__ Wupd,
                                    bf16_t* __restrict__ WtAB,
                                    bf16_t* __restrict__ WtU) {
    int idx = blockIdx.x * 256 + threadIdx.x;
    if (idx < 256 * 384) {
        int n = idx / 384;
        int k = idx - n * 384;
        float v = (n < 128) ? Wmsg[k * 128 + n] : Wrev[k * 128 + (n - 128)];
        WtAB[idx] = (bf16_t)v;
    }
    if (idx < 128 * 128) {
        int n = idx >> 7;
        int p = idx & 127;
        int colp = 32 * (p >> 5) + ((p >> 1) & 15) + 16 * (p & 1);
        WtU[idx] = (bf16_t)Wupd[colp * 128 + n];
    }
}

// ---------------------------------------------------------------------------
// CSR build: hist -> hierarchical scan (coalesced) -> inverse permutation.
// ---------------------------------------------------------------------------
__global__ void hist_kernel(const int* __restrict__ to_idx, int* __restrict__ hist) {
    int e = blockIdx.x * 256 + threadIdx.x;
    if (e < N_EDGES) atomicAdd(&hist[to_idx[e]], 1);
}

#define SCAN_CH 1000  // N_NODES = 100 blocks x 1000

__global__ __launch_bounds__(1024)
void scan_reduce_kernel(const int* __restrict__ hist, int* __restrict__ bsum) {
    __shared__ int red[1024];
    int b = blockIdx.x, t = threadIdx.x;
    int v = (t < SCAN_CH) ? hist[b * SCAN_CH + t] : 0;
    red[t] = v;
    __syncthreads();
    for (int off = 512; off > 0; off >>= 1) {
        if (t < off) red[t] += red[t + off];
        __syncthreads();
    }
    if (t == 0) bsum[b] = red[0];
}

__global__ __launch_bounds__(128)
void scan_base_kernel(const int* __restrict__ bsum, int* __restrict__ bbase) {
    __shared__ int s[128];
    int t = threadIdx.x;
    int v = (t < 100) ? bsum[t] : 0;
    s[t] = v;
    __syncthreads();
    for (int off = 1; off < 128; off <<= 1) {
        int u = (t >= off) ? s[t - off] : 0;
        __syncthreads();
        s[t] += u;
        __syncthreads();
    }
    if (t < 100) bbase[t] = s[t] - v;  // exclusive base per block
}

__global__ __launch_bounds__(1024)
void scan_final_kernel(const int* __restrict__ hist,
                       const int* __restrict__ bbase,
                       int* __restrict__ cursor,
                       int* __restrict__ row_start) {
    __shared__ int s[1024];
    int b = blockIdx.x, t = threadIdx.x;
    int v = (t < SCAN_CH) ? hist[b * SCAN_CH + t] : 0;
    s[t] = v;
    __syncthreads();
    for (int off = 1; off < 1024; off <<= 1) {
        int u = (t >= off) ? s[t - off] : 0;
        __syncthreads();
        s[t] += u;
        __syncthreads();
    }
    int excl = bbase[b] + s[t] - v;
    if (t < SCAN_CH) {
        cursor[b * SCAN_CH + t] = excl;
        row_start[b * SCAN_CH + t] = excl;
    }
    if (b == 99 && t == SCAN_CH - 1) row_start[N_NODES] = excl + v;  // = N_EDGES
}

__global__ void inv_scatter_kernel(const int* __restrict__ to_idx,
                                   int* __restrict__ cursor,
                                   int* __restrict__ inv) {
    int e = blockIdx.x * 256 + threadIdx.x;
    if (e < N_EDGES) {
        int pos = atomicAdd(&cursor[to_idx[e]], 1);
        inv[e] = pos;
    }
}

// ---------------------------------------------------------------------------
// Phase A: per block of 64 edges, K split in two 192-col halves sharing one
// 24KB LDS tile:
//   half0: [node_bf[from] | node_bf[to][0:64]]       -> LDS, MFMA ksteps 0..5
//   half1: [node_bf[to][64:128] | edgef (f32->bf16)] -> LDS, MFMA ksteps 6..11
//   relu(msg)+relu(rev), packed-bf16 store at dst-sorted position inv[e].
// __launch_bounds__(256,4): 128-VGPR cap fits acc[4][4](64)+frags(32)+addr
// WITHOUT spilling. (r5/r6 lesson: (256,6) capped VGPR at 85 -> acc spilled
// to scratch -> 27x HBM write amplification, 2.6% MfmaUtil. launch_bounds
// is a register-allocator constraint; VGPR_Count < live state = spill.)
// ---------------------------------------------------------------------------
__global__ __launch_bounds__(256, 4)
void edge_msg_kernel(const unsigned short* __restrict__ nodef_bf,
                     const float* __restrict__ edgef,
                     const int* __restrict__ from_idx,
                     const int* __restrict__ to_idx,
                     const int* __restrict__ inv,
                     const bf16_t* __restrict__ WtAB,
                     const float* __restrict__ b_msg,
                     const float* __restrict__ b_rev,
                     unsigned int* __restrict__ msgs_u) {
    __shared__ char lds_raw[64 * 384];   // [64 rows][192 cols] bf16, XOR-swizzled
    __shared__ int s_from[64], s_dst[64], s_inv[64];

    const int tid = threadIdx.x;
    const int eb = blockIdx.x * 64;

    if (tid < 64) {
        s_from[tid] = from_idx[eb + tid];
        s_dst[tid]  = to_idx[eb + tid];
        s_inv[tid]  = inv[eb + tid];
    }

    const int wv = tid >> 6;
    const int lane = tid & 63;
    const int lhi = lane >> 4;   // 0..3
    const int llo = lane & 15;   // 0..15

    f32x4 acc[4][4];
#pragma unroll
    for (int m = 0; m < 4; ++m)
#pragma unroll
        for (int n = 0; n < 4; ++n)
            acc[m][n] = (f32x4){0.f, 0.f, 0.f, 0.f};

    // B pointers: n=0,1 -> msg cols wv*32+16n ; n=2,3 -> rev cols (+128)
    const bf16_t* bptr[4];
#pragma unroll
    for (int n = 0; n < 4; ++n) {
        int colb = (n < 2) ? (wv * 32 + 16 * n) : (128 + wv * 32 + 16 * (n - 2));
        bptr[n] = WtAB + (size_t)(colb + llo) * 384 + lhi * 8;
    }

    __syncthreads();

    // ---- half 0 stage: chunks 0..23 (16B each): q<16 from, else to[0:64]
#pragma unroll
    for (int j = 0; j < 6; ++j) {
        int linear = tid + 256 * j;
        int r = linear / 24;
        int q = linear - r * 24;
        const u32x4* src = (q < 16)
            ? reinterpret_cast<const u32x4*>(nodef_bf + (size_t)s_from[r] * 128) + q
            : reinterpret_cast<const u32x4*>(nodef_bf + (size_t)s_dst[r] * 128) + (q - 16);
        u32x4 v = *src;
        int byte = (r * 384 + q * 16) ^ ((r & 7) << 4);
        *reinterpret_cast<u32x4*>(lds_raw + byte) = v;
    }
    __syncthreads();

    // ---- MFMA half 0: global ksteps 0..5
#pragma unroll
    for (int k0 = 0; k0 < 6; ++k0) {
        bf16x8 a[4], b[4];
#pragma unroll
        for (int m = 0; m < 4; ++m) {
            int ra = 16 * m + llo;
            int byte = (ra * 384 + k0 * 64 + lhi * 16) ^ ((ra & 7) << 4);
            a[m] = *reinterpret_cast<const bf16x8*>(lds_raw + byte);
        }
#pragma unroll
        for (int n = 0; n < 4; ++n)
            b[n] = *reinterpret_cast<const bf16x8*>(bptr[n] + k0 * 32);
#pragma unroll
        for (int m = 0; m < 4; ++m)
#pragma unroll
            for (int n = 0; n < 4; ++n)
                acc[m][n] = __builtin_amdgcn_mfma_f32_16x16x32_bf16(a[m], b[n], acc[m][n], 0, 0, 0);
    }
    __syncthreads();

    // ---- half 1 stage: chunks 24..47: qq<8 -> to[64:128], else edgef f32->bf16
#pragma unroll
    for (int j = 0; j < 6; ++j) {
        int linear = tid + 256 * j;
        int r = linear / 24;
        int qq = linear - r * 24;
        u32x4 w;
        if (qq < 8) {
            w = *(reinterpret_cast<const u32x4*>(nodef_bf + (size_t)s_dst[r] * 128) + 8 + qq);
        } else {
            int c = qq - 8;   // 0..15 -> source floats 8c..8c+7
            const f4* ep = reinterpret_cast<const f4*>(edgef + (size_t)(eb + r) * 128 + c * 8);
            f4 v0 = ep[0];
            f4 v1 = ep[1];
            union { bf16_t b[8]; u32x4 u; } pk;
            pk.b[0] = (bf16_t)v0[0]; pk.b[1] = (bf16_t)v0[1];
            pk.b[2] = (bf16_t)v0[2]; pk.b[3] = (bf16_t)v0[3];
            pk.b[4] = (bf16_t)v1[0]; pk.b[5] = (bf16_t)v1[1];
            pk.b[6] = (bf16_t)v1[2]; pk.b[7] = (bf16_t)v1[3];
            w = pk.u;
        }
        int byte = (r * 384 + qq * 16) ^ ((r & 7) << 4);
        *reinterpret_cast<u32x4*>(lds_raw + byte) = w;
    }
    __syncthreads();

    // ---- MFMA half 1: global ksteps 6..11
#pragma unroll
    for (int k0 = 0; k0 < 6; ++k0) {
        bf16x8 a[4], b[4];
#pragma unroll
        for (int m = 0; m < 4; ++m) {
            int ra = 16 * m + llo;
            int byte = (ra * 384 + k0 * 64 + lhi * 16) ^ ((ra & 7) << 4);
            a[m] = *reinterpret_cast<const bf16x8*>(lds_raw + byte);
        }
#pragma unroll
        for (int n = 0; n < 4; ++n)
            b[n] = *reinterpret_cast<const bf16x8*>(bptr[n] + (6 + k0) * 32);
#pragma unroll
        for (int m = 0; m < 4; ++m)
#pragma unroll
            for (int n = 0; n < 4; ++n)
                acc[m][n] = __builtin_amdgcn_mfma_f32_16x16x32_bf16(a[m], b[n], acc[m][n], 0, 0, 0);
    }

    // ---- epilogue: relu-sum both nets, pack bf16 pair, store at inv row ----
    const int c0 = wv * 32 + llo;
    const float bm0 = b_msg[c0], br0 = b_rev[c0];
    const float bm1 = b_msg[c0 + 16], br1 = b_rev[c0 + 16];
#pragma unroll
    for (int m = 0; m < 4; ++m) {
        int rbase = 16 * m + lhi * 4;
#pragma unroll
        for (int r = 0; r < 4; ++r) {
            float v0 = fmaxf(acc[m][0][r] + bm0, 0.f) + fmaxf(acc[m][2][r] + br0, 0.f);
            float v1 = fmaxf(acc[m][1][r] + bm1, 0.f) + fmaxf(acc[m][3][r] + br1, 0.f);
            union { bf16_t b[2]; unsigned int u; } pk;
            pk.b[0] = (bf16_t)v0;
            pk.b[1] = (bf16_t)v1;
            msgs_u[(size_t)s_inv[rbase + r] * 64 + wv * 16 + llo] = pk.u;
        }
    }
}

// ---------------------------------------------------------------------------
// Phase B: per block of 64 nodes:
//   f32 register segsum of each node's CONTIGUOUS msgs range (CSR),
//   -> bf16 LDS tile [64][128] (swizzled, stored-column order),
//   MFMA with pi-baked WtU, residual + relu, store out.
// ---------------------------------------------------------------------------
__global__ __launch_bounds__(256, 4)
void node_upd_kernel(const unsigned int* __restrict__ msgs_u,
                     const int* __restrict__ row_start,
                     const float* __restrict__ nodef,
                     const bf16_t* __restrict__ WtU,
                     const float* __restrict__ b_upd,
                     float* __restrict__ out) {
    __shared__ char lds_raw[64 * 256];  // [64][128] bf16, swizzled
    __shared__ int s_rs[65];

    const int tid = threadIdx.x;
    const int nb = blockIdx.x * 64;

    if (tid < 65) {
        int nid = nb + tid;
        s_rs[tid] = (nid <= N_NODES) ? row_start[nid] : N_EDGES;
    }
    __syncthreads();

    {
        const int r = tid >> 2;      // node row 0..63
        const int q = tid & 3;       // 32-column chunk
        float s[32];
#pragma unroll
        for (int i = 0; i < 32; ++i) s[i] = 0.f;
        const int rs = s_rs[r], re = s_rs[r + 1];
        for (int e = rs; e < re; ++e) {
            const u32x4* p = reinterpret_cast<const u32x4*>(msgs_u + (size_t)e * 64 + q * 16);
#pragma unroll
            for (int i = 0; i < 4; ++i) {
                u32x4 w = p[i];
                s[8*i+0] += __uint_as_float(w[0] << 16);
                s[8*i+1] += __uint_as_float(w[0] & 0xffff0000u);
                s[8*i+2] += __uint_as_float(w[1] << 16);
                s[8*i+3] += __uint_as_float(w[1] & 0xffff0000u);
                s[8*i+4] += __uint_as_float(w[2] << 16);
                s[8*i+5] += __uint_as_float(w[2] & 0xffff0000u);
                s[8*i+6] += __uint_as_float(w[3] << 16);
                s[8*i+7] += __uint_as_float(w[3] & 0xffff0000u);
            }
        }
        // bf16-pack into LDS (swizzled), stored-column order
#pragma unroll
        for (int i = 0; i < 4; ++i) {
            union { bf16_t b[8]; u32x4 u; } pk;
#pragma unroll
            for (int w = 0; w < 8; ++w) pk.b[w] = (bf16_t)s[8*i + w];
            int byte = (r * 256 + q * 64 + i * 16) ^ ((r & 7) << 4);
            *reinterpret_cast<u32x4*>(lds_raw + byte) = pk.u;
        }
    }
    __syncthreads();

    const int wv = tid >> 6;
    const int lane = tid & 63;
    const int lhi = lane >> 4;
    const int llo = lane & 15;

    f32x4 acc[4][2];
#pragma unroll
    for (int m = 0; m < 4; ++m)
#pragma unroll
        for (int n = 0; n < 2; ++n)
            acc[m][n] = (f32x4){0.f, 0.f, 0.f, 0.f};

#pragma unroll
    for (int k0 = 0; k0 < 4; ++k0) {
        bf16x8 a[4], b[2];
#pragma unroll
        for (int m = 0; m < 4; ++m) {
            int ra = 16 * m + llo;
            int byte = (ra * 256 + (k0 * 32 + lhi * 8) * 2) ^ ((ra & 7) << 4);
            a[m] = *reinterpret_cast<const bf16x8*>(lds_raw + byte);
        }
#pragma unroll
        for (int n = 0; n < 2; ++n) {
            int col = wv * 32 + 16 * n + llo;
            b[n] = *reinterpret_cast<const bf16x8*>(WtU + (size_t)col * 128 + k0 * 32 + lhi * 8);
        }
#pragma unroll
        for (int m = 0; m < 4; ++m)
#pragma unroll
            for (int n = 0; n < 2; ++n)
                acc[m][n] = __builtin_amdgcn_mfma_f32_16x16x32_bf16(a[m], b[n], acc[m][n], 0, 0, 0);
    }

#pragma unroll
    for (int m = 0; m < 4; ++m) {
        int rbase = 16 * m + lhi * 4;
#pragma unroll
        for (int r = 0; r < 4; ++r) {
            int i = nb + rbase + r;
            if (i < N_NODES) {
#pragma unroll
                for (int n = 0; n < 2; ++n) {
                    int c = wv * 32 + 16 * n + llo;
                    out[(size_t)i * 128 + c] =
                        nodef[(size_t)i * 128 + c]
                        + fmaxf(acc[m][n][r] + b_upd[c], 0.f);
                }
            }
        }
    }
}

// ---------------------------------------------------------------------------
extern "C" void kernel_launch(void* const* d_in, const int* in_sizes, int n_in,
                              void* d_out, int out_size, void* d_ws, size_t ws_size,
                              hipStream_t stream) {
    const float* nodef    = (const float*)d_in[0];
    const float* edgef    = (const float*)d_in[1];
    const int*   from_idx = (const int*)d_in[2];
    const int*   to_idx   = (const int*)d_in[3];
    const float* Wmsg     = (const float*)d_in[4];
    const float* bmsg     = (const float*)d_in[5];
    const float* Wrev     = (const float*)d_in[6];
    const float* brev     = (const float*)d_in[7];
    const float* Wupd     = (const float*)d_in[8];
    const float* bupd     = (const float*)d_in[9];
    float* out = (float*)d_out;

    char* ws = (char*)d_ws;
    unsigned int*   msgs_u   = (unsigned int*)ws;              // 163,840,000 B
    bf16_t*         WtAB     = (bf16_t*)(ws + 163840000);      // 196,608 B
    bf16_t*         WtU      = (bf16_t*)(ws + 164036608);      // 32,768 B
    unsigned short* nodef_bf = (unsigned short*)(ws + 164069376); // 25,600,000 B
    int*            hist     = (int*)(ws + 189669376);         // 400,000 B
    int*            cursor   = (int*)(ws + 190069376);         // 400,000 B
    int*            rowstart = (int*)(ws + 190469376);         // 400,016 B
    int*            inv      = (int*)(ws + 190869392);         // 2,560,000 B
    int*            bsum     = (int*)(ws + 193429392);         // 400 B
    int*            bbase    = (int*)(ws + 193429792);         // 400 B
                                                               // total ~193.4 MB

    hipMemsetAsync(hist, 0, (size_t)N_NODES * sizeof(int), stream);

    convert_nodef_kernel<<<12500, 256, 0, stream>>>(nodef, nodef_bf);
    prep_weights_kernel<<<384, 256, 0, stream>>>(Wmsg, Wrev, Wupd, WtAB, WtU);
    hist_kernel<<<(N_EDGES + 255) / 256, 256, 0, stream>>>(to_idx, hist);
    scan_reduce_kernel<<<100, 1024, 0, stream>>>(hist, bsum);
    scan_base_kernel<<<1, 128, 0, stream>>>(bsum, bbase);
    scan_final_kernel<<<100, 1024, 0, stream>>>(hist, bbase, cursor, rowstart);
    inv_scatter_kernel<<<(N_EDGES + 255) / 256, 256, 0, stream>>>(to_idx, cursor, inv);
    edge_msg_kernel<<<N_EDGES / 64, 256, 0, stream>>>(
        nodef_bf, edgef, from_idx, to_idx, inv, WtAB, bmsg, brev, msgs_u);
    node_upd_kernel<<<(N_NODES + 63) / 64, 256, 0, stream>>>(
        msgs_u, rowstart, nodef, WtU, bupd, out);
}